// Round 31
// baseline (218.438 us; speedup 1.0000x reference)
//
#include <hip/hip_runtime.h>
#include <hip/hip_bf16.h>
#include <math.h>

#define E 1024
#define NEXP 16
#define HH 8
#define DD 128
#define SS 256
#define BB 2
#define TT 2048
#define BT 4096      // BB*TT

typedef __attribute__((ext_vector_type(8))) short bf16x8;
typedef __attribute__((ext_vector_type(4))) float f32x4;

#define GLDS16(g, s) __builtin_amdgcn_global_load_lds( \
    (const __attribute__((address_space(1))) void*)(g), \
    (__attribute__((address_space(3))) void*)(s), 16, 0, 0)

__device__ __forceinline__ ushort f2b(float f) {
    union { float f; unsigned u; } v; v.f = f;
    unsigned r = (v.u + 0x7FFFu + ((v.u >> 16) & 1u)) >> 16;
    return (ushort)r;
}
__device__ __forceinline__ float b2f(ushort u) {
    union { unsigned u; float f; } v; v.u = ((unsigned)u) << 16;
    return v.f;
}
// tanh-form gelu: x * sigmoid(2*0.79788456*(x + 0.044715 x^3)); err <1e-4 at |x|<1
__device__ __forceinline__ float gelu_fast(float x) {
    float u2 = x * x;
    float tu = x * (1.5957691216f + 0.0713548163f * u2);   // 2u
    float e = __expf(tu);
    float sig = 1.f - __builtin_amdgcn_rcpf(e + 1.f);      // e/(e+1)
    return x * sig;
}

// ---------------------------------------------------------------------------
// PREP (fused): blocks [0,2048) w_in->wib swz; [2048,3072) w_out->wob;
// [3072,3584) expert K/V -> kfb/vtf; [3584,4608) ROUTER (logits+top2+xb).
// ---------------------------------------------------------------------------
__global__ __launch_bounds__(256) void prep(
    const float* __restrict__ w_in, const float* __restrict__ w_out,
    const float* __restrict__ kf, const float* __restrict__ vf,
    const float* __restrict__ x,
    ushort* __restrict__ wib, ushort* __restrict__ wob,
    ushort* __restrict__ kfb, ushort* __restrict__ vtf,
    float* __restrict__ gval, int* __restrict__ eidx, ushort* __restrict__ xb)
{
    __shared__ float T[64][132];
    const int bx = blockIdx.x;
    const int t = threadIdx.x;

    if (bx >= 3584) {
        // ---- router part: 4 tokens per block, wave = one token ----
        const int m = (bx - 3584) * 4 + (t >> 6);
        const int lane = t & 63;

        const float* xp = x + (size_t)m * 1024 + lane * 4;
        float4 xv0 = *(const float4*)(xp);
        float4 xv1 = *(const float4*)(xp + 256);
        float4 xv2 = *(const float4*)(xp + 512);
        float4 xv3 = *(const float4*)(xp + 768);

        {
            const int swrow = (m & 7) << 4;
            char* xrow = (char*)xb + (size_t)m * 2048;
            ushort4 u;
            u.x = f2b(xv0.x); u.y = f2b(xv0.y); u.z = f2b(xv0.z); u.w = f2b(xv0.w);
            *(ushort4*)(xrow + ((lane * 8 + 0 * 512) ^ swrow)) = u;
            u.x = f2b(xv1.x); u.y = f2b(xv1.y); u.z = f2b(xv1.z); u.w = f2b(xv1.w);
            *(ushort4*)(xrow + ((lane * 8 + 1 * 512) ^ swrow)) = u;
            u.x = f2b(xv2.x); u.y = f2b(xv2.y); u.z = f2b(xv2.z); u.w = f2b(xv2.w);
            *(ushort4*)(xrow + ((lane * 8 + 2 * 512) ^ swrow)) = u;
            u.x = f2b(xv3.x); u.y = f2b(xv3.y); u.z = f2b(xv3.z); u.w = f2b(xv3.w);
            *(ushort4*)(xrow + ((lane * 8 + 3 * 512) ^ swrow)) = u;
        }

        float p[16];
        #pragma unroll
        for (int e = 0; e < 16; ++e) {
            const float* wp = w_in + (size_t)(4096 + e) * 1024 + lane * 4;
            float4 w0 = *(const float4*)(wp);
            float4 w1 = *(const float4*)(wp + 256);
            float4 w2 = *(const float4*)(wp + 512);
            float4 w3 = *(const float4*)(wp + 768);
            float s0 = xv0.x * w0.x + xv0.y * w0.y + xv0.z * w0.z + xv0.w * w0.w;
            float s1 = xv1.x * w1.x + xv1.y * w1.y + xv1.z * w1.z + xv1.w * w1.w;
            float s2 = xv2.x * w2.x + xv2.y * w2.y + xv2.z * w2.z + xv2.w * w2.w;
            float s3 = xv3.x * w3.x + xv3.y * w3.y + xv3.z * w3.z + xv3.w * w3.w;
            p[e] = (s0 + s1) + (s2 + s3);
        }
        #pragma unroll
        for (int d = 1; d < 64; d <<= 1) {
            #pragma unroll
            for (int e = 0; e < 16; ++e)
                p[e] += __shfl_xor(p[e], d);
        }
        float best = -1e30f; int bi = 0;
        #pragma unroll
        for (int e = 0; e < 16; ++e)
            if (p[e] > best) { best = p[e]; bi = e; }
        float best2 = -1e30f; int bi2 = 0;
        #pragma unroll
        for (int e = 0; e < 16; ++e)
            if (e != bi && p[e] > best2) { best2 = p[e]; bi2 = e; }

        if (lane == 0) {
            gval[m * 2 + 0] = 1.f / (1.f + __expf(-best));
            gval[m * 2 + 1] = 1.f / (1.f + __expf(-best2));
            eidx[m * 2 + 0] = bi;
            eidx[m * 2 + 1] = bi2;
        }
        return;
    }

    if (bx < 3072) {
        const float* in;
        ushort* outp;
        int kshift, i;
        if (bx < 2048) { in = w_in;  outp = wib; kshift = 10; i = (bx * 256 + t) * 8; }
        else           { in = w_out; outp = wob; kshift = 11; i = ((bx - 2048) * 256 + t) * 8; }
        int row = i >> kshift;
        int colb = (i - (row << kshift)) * 2;
        float4 f0 = *(const float4*)(in + i);
        float4 f1 = *(const float4*)(in + i + 4);
        ushort4 u0, u1;
        u0.x = f2b(f0.x); u0.y = f2b(f0.y); u0.z = f2b(f0.z); u0.w = f2b(f0.w);
        u1.x = f2b(f1.x); u1.y = f2b(f1.y); u1.z = f2b(f1.z); u1.w = f2b(f1.w);
        char* dst = (char*)outp + ((size_t)row << (kshift + 1)) + (colb ^ ((row & 7) << 4));
        *(ushort4*)dst = u0;
        *(ushort4*)(dst + 8) = u1;
        return;
    }

    // cvt_kv part
    const int idx = bx - 3072;
    const int st = idx & 3, eh = idx >> 2;
    const int s0 = st * 64;
    const float* kbp = kf + (size_t)eh * SS * DD + (size_t)s0 * DD;
    const float* vbp = vf + (size_t)eh * SS * DD + (size_t)s0 * DD;
    for (int i = t; i < 64 * 32; i += 256) {
        int r = i >> 5, c4 = i & 31;
        float4 f = *(const float4*)(kbp + (size_t)r * DD + c4 * 4);
        ushort4 u;
        u.x = f2b(f.x); u.y = f2b(f.y); u.z = f2b(f.z); u.w = f2b(f.w);
        *(ushort4*)((char*)kfb + ((size_t)eh * 256 + s0 + r) * 256 + ((c4 * 8) ^ ((r & 7) << 4))) = u;
    }
    for (int i = t; i < 64 * 32; i += 256) {
        int r = i >> 5, c4 = i & 31;
        float4 f = *(const float4*)(vbp + (size_t)r * DD + c4 * 4);
        T[r][c4 * 4 + 0] = f.x; T[r][c4 * 4 + 1] = f.y;
        T[r][c4 * 4 + 2] = f.z; T[r][c4 * 4 + 3] = f.w;
    }
    __syncthreads();
    int g = t >> 4, fr = t & 15;
    #pragma unroll
    for (int dd = 0; dd < 8; ++dd) {
        int d = g + dd * 16;
        ushort4 u;
        u.x = f2b(T[4 * fr + 0][d]); u.y = f2b(T[4 * fr + 1][d]);
        u.z = f2b(T[4 * fr + 2][d]); u.w = f2b(T[4 * fr + 3][d]);
        size_t ob = ((size_t)eh * 128 + d) * 512 + s0 * 2;
        *(ushort4*)((char*)vtf + ob + ((8 * fr) ^ ((d & 7) << 4))) = u;
    }
}

// ---------------------------------------------------------------------------
// bf16 MFMA GEMM (generic, used for gemm2): C = A*B^T, operands pre-swizzled.
// ---------------------------------------------------------------------------
template<int BF16OUT>
__global__ __launch_bounds__(256) void gemm_bf16(
    const ushort* __restrict__ A, int lda,
    const ushort* __restrict__ B, int ldb,
    void* __restrict__ Cv, int ldc, int K)
{
    __shared__ ushort As[128 * 64];
    __shared__ ushort Bs[128 * 64];
    const int t = threadIdx.x;
    const int l = t & 63, w = t >> 6;
    const int m0 = blockIdx.y * 128, n0 = blockIdx.x * 128;
    const int wr = w >> 1, wc = w & 1;
    const int fr = l & 15, fg = l >> 4;

    const int srow = w * 32 + (l >> 3);
    const int sboff = (l & 7) * 16;
    const char* Ag = (const char*)A + ((size_t)(m0 + srow) * lda) * 2 + sboff;
    const char* Bg = (const char*)B + ((size_t)(n0 + srow) * ldb) * 2 + sboff;
    const int aswz = (fr & 7) << 4;

    f32x4 acc[4][4];
    #pragma unroll
    for (int i = 0; i < 4; ++i)
        #pragma unroll
        for (int j = 0; j < 4; ++j) { acc[i][j][0]=0.f; acc[i][j][1]=0.f; acc[i][j][2]=0.f; acc[i][j][3]=0.f; }

    for (int k0b = 0; k0b < K * 2; k0b += 128) {
        #pragma unroll
        for (int i = 0; i < 4; ++i) {
            GLDS16(Ag + (size_t)(i * 8) * lda * 2 + k0b, (char*)As + (w * 32 + i * 8) * 128);
            GLDS16(Bg + (size_t)(i * 8) * ldb * 2 + k0b, (char*)Bs + (w * 32 + i * 8) * 128);
        }
        __syncthreads();
        #pragma unroll
        for (int ksub = 0; ksub < 2; ++ksub) {
            bf16x8 a[4], b[4];
            #pragma unroll
            for (int mi = 0; mi < 4; ++mi)
                a[mi] = *(const bf16x8*)((const char*)As + (wr * 64 + mi * 16 + fr) * 128 + ((ksub * 64 + fg * 16) ^ aswz));
            #pragma unroll
            for (int ni = 0; ni < 4; ++ni)
                b[ni] = *(const bf16x8*)((const char*)Bs + (wc * 64 + ni * 16 + fr) * 128 + ((ksub * 64 + fg * 16) ^ aswz));
            #pragma unroll
            for (int mi = 0; mi < 4; ++mi)
                #pragma unroll
                for (int ni = 0; ni < 4; ++ni)
                    acc[mi][ni] = __builtin_amdgcn_mfma_f32_16x16x32_bf16(a[mi], b[ni], acc[mi][ni], 0, 0, 0);
        }
        __syncthreads();
    }
    #pragma unroll
    for (int mi = 0; mi < 4; ++mi)
        #pragma unroll
        for (int ni = 0; ni < 4; ++ni) {
            const int row = m0 + wr * 64 + mi * 16 + fg * 4;
            const int col = n0 + wc * 64 + ni * 16 + fr;
            #pragma unroll
            for (int r = 0; r < 4; ++r) {
                if (BF16OUT)
                    ((ushort*)Cv)[(size_t)(row + r) * ldc + col] = f2b(acc[mi][ni][r]);
                else
                    ((float*)Cv)[(size_t)(row + r) * ldc + col] = acc[mi][ni][r];
            }
        }
}

// ---------------------------------------------------------------------------
// gemm1 FUSED + build_lists rider (riders at END; 2-phase wave-local scan).
//   lin < 1024:  gemm1 (bxn = lin&31, by = lin>>5), epilogue by region
//   lin >= 1024: build_lists for expert e = lin-1024
// Regions 0 & 3 stage through sh and write FULL 128-B lines per wave instr.
// ---------------------------------------------------------------------------
__global__ __launch_bounds__(256) void gemm1_fused(
    const ushort* __restrict__ A, const ushort* __restrict__ B,
    ushort* __restrict__ hbq,
    ushort* __restrict__ qb, ushort* __restrict__ kb,
    ushort* __restrict__ vtb,
    const int* __restrict__ eidx,
    int* __restrict__ counts, int* __restrict__ plist)
{
    __shared__ ushort sh[128 * 128];     // 32 KB: As|Bs during loop, Ts after
    const int lin = blockIdx.x;
    const int t = threadIdx.x;

    if (lin >= 1024) {
        // ---- build_lists (expert e): each wave owns tokens [w*2048,(w+1)*2048)
        int* ish = (int*)sh;             // ish[0..3] = per-wave counts
        const int e = lin - 1024;
        const int w = t >> 6, lane = t & 63;
        const int base = w * 2048;

        int cnt = 0;
        for (int c = 0; c < 2048; c += 64) {
            bool match = (eidx[base + c + lane] == e);
            unsigned long long mask = __ballot(match);
            cnt += __popcll(mask);
        }
        if (lane == 0) ish[w] = cnt;
        __syncthreads();
        int off = 0;
        #pragma unroll
        for (int i = 0; i < 4; ++i) if (i < w) off += ish[i];
        for (int c = 0; c < 2048; c += 64) {
            bool match = (eidx[base + c + lane] == e);
            unsigned long long mask = __ballot(match);
            int lpre = __popcll(mask & ((1ull << lane) - 1ull));
            if (match) plist[e * BT + off + lpre] = base + c + lane;
            off += __popcll(mask);
        }
        if (t == 0) counts[e] = ish[0] + ish[1] + ish[2] + ish[3];
        return;
    }

    ushort* As = sh;
    ushort* Bs = sh + 128 * 64;
    const int l = t & 63, w = t >> 6;
    const int bxn = lin & 31, by = lin >> 5;
    const int m0 = by * 128, n0 = bxn * 128;
    const int wr = w >> 1, wc = w & 1;
    const int fr = l & 15, fg = l >> 4;

    const int srow = w * 32 + (l >> 3);
    const int sboff = (l & 7) * 16;
    const char* Ag = (const char*)A + ((size_t)(m0 + srow) * 1024) * 2 + sboff;
    const char* Bg = (const char*)B + ((size_t)(n0 + srow) * 1024) * 2 + sboff;
    const int aswz = (fr & 7) << 4;

    f32x4 acc[4][4];
    #pragma unroll
    for (int i = 0; i < 4; ++i)
        #pragma unroll
        for (int j = 0; j < 4; ++j) { acc[i][j][0]=0.f; acc[i][j][1]=0.f; acc[i][j][2]=0.f; acc[i][j][3]=0.f; }

    for (int k0b = 0; k0b < 2048; k0b += 128) {
        #pragma unroll
        for (int i = 0; i < 4; ++i) {
            GLDS16(Ag + (size_t)(i * 8) * 2048 + k0b, (char*)As + (w * 32 + i * 8) * 128);
            GLDS16(Bg + (size_t)(i * 8) * 2048 + k0b, (char*)Bs + (w * 32 + i * 8) * 128);
        }
        __syncthreads();
        #pragma unroll
        for (int ksub = 0; ksub < 2; ++ksub) {
            bf16x8 a[4], b[4];
            #pragma unroll
            for (int mi = 0; mi < 4; ++mi)
                a[mi] = *(const bf16x8*)((const char*)As + (wr * 64 + mi * 16 + fr) * 128 + ((ksub * 64 + fg * 16) ^ aswz));
            #pragma unroll
            for (int ni = 0; ni < 4; ++ni)
                b[ni] = *(const bf16x8*)((const char*)Bs + (wc * 64 + ni * 16 + fr) * 128 + ((ksub * 64 + fg * 16) ^ aswz));
            #pragma unroll
            for (int mi = 0; mi < 4; ++mi)
                #pragma unroll
                for (int ni = 0; ni < 4; ++ni)
                    acc[mi][ni] = __builtin_amdgcn_mfma_f32_16x16x32_bf16(a[mi], b[ni], acc[mi][ni], 0, 0, 0);
        }
        __syncthreads();
    }

    const int region = bxn >> 3;   // 0=qf 1=q 2=k 3=v
    const int hd = bxn & 7;

    if (region == 0) {
        #pragma unroll
        for (int mi = 0; mi < 4; ++mi)
            #pragma unroll
            for (int ni = 0; ni < 4; ++ni) {
                const int cl = wc * 64 + ni * 16 + fr;
                #pragma unroll
                for (int r = 0; r < 4; ++r) {
                    const int rl = wr * 64 + mi * 16 + fg * 4 + r;
                    sh[rl * 128 + (cl ^ ((rl & 7) << 4))] = f2b(acc[mi][ni][r]);
                }
            }
        __syncthreads();
        const int r8 = l >> 3, u = l & 7;
        #pragma unroll
        for (int it = 0; it < 8; ++it) {
            const int slot = it * 4 + w;           // 0..31
            const int row = (slot & 15) * 8 + r8;  // 0..127
            const int c0 = (slot >> 4) * 64 + u * 8;
            bf16x8 v = *(const bf16x8*)&sh[row * 128 + (c0 ^ ((row & 7) << 4))];
            *(bf16x8*)&hbq[(size_t)(m0 + row) * 1024 + n0 + c0] = v;
        }
    } else if (region == 3) {
        const int bt = m0 >> 11;
        const int bh = bt * 8 + hd;
        const int tokbase = m0 & 2047;
        #pragma unroll
        for (int mi = 0; mi < 4; ++mi)
            #pragma unroll
            for (int ni = 0; ni < 4; ++ni) {
                const int cl = wc * 64 + ni * 16 + fr;    // d
                #pragma unroll
                for (int r = 0; r < 4; ++r) {
                    const int rl = wr * 64 + mi * 16 + fg * 4 + r;  // tok_local
                    sh[rl * 128 + ((cl + rl) & 127)] = f2b(acc[mi][ni][r]);
                }
            }
        __syncthreads();
        const int u = l & 7;          // memory unit (16 B) within 128-B segment
        #pragma unroll
        for (int it = 0; it < 8; ++it) {
            const int slot = it * 4 + w;            // 0..31
            const int dbase = (slot & 15) * 8;      // 0..120
            const int seg = slot >> 4;              // 0..1
            const int d = dbase + (l >> 3);
            const int tu = u ^ (d & 7);             // tok-unit feeding mem unit u
            bf16x8 v;
            #pragma unroll
            for (int j = 0; j < 8; ++j) {
                const int tl = seg * 64 + tu * 8 + j;
                v[j] = (short)sh[tl * 128 + ((d + tl) & 127)];
            }
            char* dst = (char*)vtb + (size_t)(bh * 128 + d) * 4096
                      + ((tokbase >> 6) + seg) * 128 + u * 16;
            *(bf16x8*)dst = v;
        }
    } else {
        #pragma unroll
        for (int mi = 0; mi < 4; ++mi)
            #pragma unroll
            for (int ni = 0; ni < 4; ++ni) {
                const int rl = wr * 64 + mi * 16 + fg * 4;
                const int cl = wc * 64 + ni * 16 + fr;
                #pragma unroll
                for (int r = 0; r < 4; ++r)
                    sh[(rl + r) * 128 + cl] = f2b(acc[mi][ni][r]);
            }
        __syncthreads();
        ushort* outb = (region == 1) ? qb : kb;
        #pragma unroll
        for (int it = 0; it < 4; ++it) {
            const int item = it * 256 + t;
            const int rloc = item >> 3, g = item & 7;
            const int rowg = m0 + rloc;
            const int tok = rowg & 2047, bt = rowg >> 11;
            const int sw = (tok & 7) << 4;
            char* rowbase = (char*)outb + ((size_t)((bt * 8 + hd) * 2048 + tok)) * 256;
            ushort lo[8], hi[8];
            #pragma unroll
            for (int jj = 0; jj < 8; ++jj) {
                const int j = g * 8 + jj;
                float t1 = b2f(sh[rloc * 128 + j]);
                float t2 = b2f(sh[rloc * 128 + 64 + j]);
                float invf = __expf(-(float)j * (9.210340371976184f / 64.f));
                float ang = (float)tok * invf;
                float s, c;
                sincosf(ang, &s, &c);
                lo[jj] = f2b(t1 * c - t2 * s);
                hi[jj] = f2b(t1 * s + t2 * c);
            }
            *(ushort4*)(rowbase + ((16 * g) ^ sw))        = *(ushort4*)&lo[0];
            *(ushort4*)(rowbase + (((16 * g) ^ sw) + 8))  = *(ushort4*)&lo[4];
            *(ushort4*)(rowbase + ((16 * g + 128) ^ sw))       = *(ushort4*)&hi[0];
            *(ushort4*)(rowbase + (((16 * g + 128) ^ sw) + 8)) = *(ushort4*)&hi[4];
        }
    }
}

// ---------------------------------------------------------------------------
// ATTN + FFN merged dispatch (independent jobs, disjoint block ranges).
//   lin < 256:   MFMA flash attention v5 (8 waves = 512 threads)
//   lin >= 256:  MoE FFN (waves 0-3 active; waves 4-7 exit after barrier)
// P-tile row stride = 68 ushorts (136 B, 34 words ≡ 2 mod 32): PV A-read
// drops from 8-way to 4-way bank conflict; P-writes become ~conflict-free.
// ---------------------------------------------------------------------------
__global__ __launch_bounds__(512, 1) void attn_ffn(
    const ushort* __restrict__ qb, const ushort* __restrict__ kb,
    const ushort* __restrict__ vtb, ushort* __restrict__ catb,
    const ushort* __restrict__ hbq,
    const float* __restrict__ gv,
    const int* __restrict__ counts,
    const int* __restrict__ plist,
    const ushort* __restrict__ kfb, const ushort* __restrict__ vtf,
    ushort* __restrict__ pairout)
{
    __shared__ __align__(16) char smem[156672];
    const int t = threadIdx.x, l = t & 63, w = t >> 6;
    const int fr = l & 15, fg = l >> 4;
    const int lin = blockIdx.x;

    if (lin < 256) {
        // =========================== attention ===========================
        // carve: Ks[2] @0 (65536), Vs[2] @65536 (65536), Ps @131072 (17408
        // = 8 waves x 16 x 68 ushorts), LlS @148480 (512)
        ushort* Psb  = (ushort*)(smem + 131072);
        float*  LlSb = (float*)(smem + 148480);

        const int wl = w & 3, hh = w >> 2;
        const int bh = (lin & 7) * 2 + (lin >> 7);
        const int tpair = (lin >> 3) & 15;
        const int swz = (fr & 7) << 4;
        ushort* Pw = Psb + w * (16 * 68);

        #pragma unroll 1
        for (int pass = 0; pass < 2; ++pass) {
            const int qt = pass ? (31 - tpair) : tpair;
            const int qbase = qt * 64;
            const int nkt = (qt + 2) >> 1;          // 128-kv tiles
            const int qg = qbase + wl * 16 + fg * 4;

            bf16x8 qreg[4];
            {
                const char* qrow = (const char*)qb + ((size_t)(bh * 2048 + qbase + wl * 16 + fr)) * 256;
                #pragma unroll
                for (int ks = 0; ks < 4; ++ks)
                    qreg[ks] = *(const bf16x8*)(qrow + ((ks * 64 + fg * 16) ^ swz));
            }
            {
                const char* ksrc = (const char*)kb + ((size_t)(bh * 2048 + w * 16)) * 256;
                const char* vsrc = (const char*)vtb + ((size_t)(bh * 128 + w * 16)) * 4096;
                #pragma unroll
                for (int i = 0; i < 4; ++i) {
                    GLDS16(ksrc + (size_t)(i * 4 + (l >> 4)) * 256 + (l & 15) * 16,
                           smem + (w * 16 + i * 4) * 256);
                    GLDS16(vsrc + (size_t)(i * 4 + (l >> 4)) * 4096 + (l & 15) * 16,
                           smem + 65536 + (w * 16 + i * 4) * 256);
                }
            }

            f32x4 po[8];
            #pragma unroll
            for (int i = 0; i < 8; ++i) { po[i][0]=0.f; po[i][1]=0.f; po[i][2]=0.f; po[i][3]=0.f; }
            float lrow[4] = {0.f, 0.f, 0.f, 0.f};

            asm volatile("s_waitcnt vmcnt(0)" ::: "memory");
            __syncthreads();

            for (int kt = 0; kt < nkt; ++kt) {
                const int cur = kt & 1;
                if (kt + 1 < nkt) {
                    const int kvn = (kt + 1) * 128;
                    const char* ksrc = (const char*)kb + ((size_t)(bh * 2048 + kvn + w * 16)) * 256;
                    const char* vsrc = (const char*)vtb + ((size_t)(bh * 128 + w * 16)) * 4096 + kvn * 2;
                    #pragma unroll
                    for (int i = 0; i < 4; ++i) {
                        GLDS16(ksrc + (size_t)(i * 4 + (l >> 4)) * 256 + (l & 15) * 16,
                               smem + (cur ^ 1) * 32768 + (w * 16 + i * 4) * 256);
                        GLDS16(vsrc + (size_t)(i * 4 + (l >> 4)) * 4096 + (l & 15) * 16,
                               smem + 65536 + (cur ^ 1) * 32768 + (w * 16 + i * 4) * 256);
                    }
                }
                const int kvb = kt * 128;

                f32x4 s[4];
                #pragma unroll
                for (int i = 0; i < 4; ++i) { s[i][0]=0.f; s[i][1]=0.f; s[i][2]=0.f; s[i][3]=0.f; }
                __builtin_amdgcn_s_setprio(1);
                #pragma unroll
                for (int ks = 0; ks < 4; ++ks) {
                    #pragma unroll
                    for (int fn = 0; fn < 4; ++fn) {
                        const int brow = hh * 64 + fn * 16 + fr;
                        bf16x8 bb = *(const bf16x8*)(smem + cur * 32768 + brow * 256 + ((ks * 64 + fg * 16) ^ swz));
                        s[fn] = __builtin_amdgcn_mfma_f32_16x16x32_bf16(qreg[ks], bb, s[fn], 0, 0, 0);
                    }
                }
                __builtin_amdgcn_s_setprio(0);

                const int colbase = kvb + hh * 64;
                const bool needmask = (colbase + 64 > qbase + wl * 16);
                float ps[4] = {0.f, 0.f, 0.f, 0.f};
                #pragma unroll
                for (int fn = 0; fn < 4; ++fn)
                    #pragma unroll
                    for (int r = 0; r < 4; ++r) {
                        float v = s[fn][r] * 0.08838834764831845f;
                        bool masked = needmask && (colbase + fn * 16 + fr > qg + r);
                        float p = masked ? 0.f : __expf(v);
                        ps[r] += p;
                        Pw[(fg * 4 + r) * 68 + fn * 16 + fr] = f2b(p);
                    }
                #pragma unroll
                for (int r = 0; r < 4; ++r) {
                    float s2 = ps[r];
                    s2 += __shfl_xor(s2, 1);
                    s2 += __shfl_xor(s2, 2);
                    s2 += __shfl_xor(s2, 4);
                    s2 += __shfl_xor(s2, 8);
                    lrow[r] += s2;
                }

                asm volatile("s_waitcnt lgkmcnt(0)" ::: "memory");
                __builtin_amdgcn_sched_barrier(0);

                __builtin_amdgcn_s_setprio(1);
                #pragma unroll
                for (int ks2 = 0; ks2 < 2; ++ks2) {
                    bf16x8 pa = *(const bf16x8*)((const char*)Pw + fr * 136 + ks2 * 64 + fg * 16);
                    #pragma unroll
                    for (int fn2 = 0; fn2 < 8; ++fn2) {
                        const int vrow = fn2 * 16 + fr;
                        bf16x8 bv = *(const bf16x8*)(smem + 65536 + cur * 32768 + vrow * 256 + ((hh * 128 + ks2 * 64 + fg * 16) ^ swz));
                        po[fn2] = __builtin_amdgcn_mfma_f32_16x16x32_bf16(pa, bv, po[fn2], 0, 0, 0);
                    }
                }
                __builtin_amdgcn_s_setprio(0);

                asm volatile("s_waitcnt vmcnt(0)" ::: "memory");
                __syncthreads();
            }

            // ---- epilogue: plain two-way sum merge (no max tracking) ----
            if (fr == 0) {
                #pragma unroll
                for (int r = 0; r < 4; ++r)
                    LlSb[w * 16 + fg * 4 + r] = lrow[r];
            }
            __syncthreads();
            float linv[4];
            #pragma unroll
            for (int r = 0; r < 4; ++r)
                linv[r] = 1.f / (lrow[r] + LlSb[(w ^ 4) * 16 + fg * 4 + r]);
            float* PO = (float*)smem;   // 32 KB scratch (K buffers dead here)
            if (hh == 1) {
                #pragma unroll
                for (int fn2 = 0; fn2 < 8; ++fn2)
                    #pragma unroll
                    for (int r = 0; r < 4; ++r)
                        PO[(wl * 16 + fg * 4 + r) * 128 + fn2 * 16 + fr] = po[fn2][r];
            }
            __syncthreads();
            if (hh == 0) {
                const int mg = (bh >> 3) * 2048 + qbase + wl * 16 + fg * 4;
                #pragma unroll
                for (int r = 0; r < 4; ++r) {
                    const int rswz = ((mg + r) & 7) << 4;
                    #pragma unroll
                    for (int fn2 = 0; fn2 < 8; ++fn2) {
                        float v = po[fn2][r] + PO[(wl * 16 + fg * 4 + r) * 128 + fn2 * 16 + fr];
                        int colb = ((bh & 7) * 128 + fn2 * 16 + fr) * 2;
                        *(ushort*)((char*)catb + (size_t)(mg + r) * 4096 + (colb ^ rswz)) = f2b(v * linv[r]);
                    }
                }
            }
            __syncthreads();   // protect Ks reuse before next pass's staging
        }
        return;
    }

    // ============================== ffn ==============================
    {
        // carve: Ks @0 (65536), Vs @65536 (65536), Qs @131072 (16384),
        // Ps @147456 (8704 = 4 waves x 16 x 68 ushorts)
        ushort* Qs  = (ushort*)(smem + 131072);
        ushort* Psb = (ushort*)(smem + 147456);

        const int idx = lin - 256;
        const int half = idx & 1, hd = (idx >> 1) & 7, e = idx >> 4;
        const int eh = e * HH + hd;
        const int n_e = counts[e];

        if (w < 4) {
            const char* kbase = (const char*)kfb + (size_t)eh * 65536;
            const char* vbase = (const char*)vtf + (size_t)eh * 65536;
            #pragma unroll
            for (int i = 0; i < 16; ++i) {
                GLDS16(kbase + (w * 64 + i * 4) * 256 + l * 16, smem + (w * 64 + i * 4) * 256);
                GLDS16(vbase + w * 16384 + i * 1024 + l * 16, smem + 65536 + w * 16384 + i * 1024);
            }
        }
        __syncthreads();
        if (w >= 4) return;

        const int arow = w * 16 + fr;
        const int aswz = (arow & 7) << 4;
        ushort* Pw = Psb + w * (16 * 68);
        const int rl4 = l >> 4;
        const int lb = (l & 15) * 16;

        for (int tb = half * 64; tb < n_e; tb += 128) {
            #pragma unroll
            for (int i = 0; i < 4; ++i) {
                int row = w * 16 + i * 4 + rl4;
                int gr = tb + row;
                int p = plist[e * BT + min(gr, n_e - 1)];
                int m = p >> 1;
                const char* src = (const char*)hbq + (size_t)m * 2048 + hd * 256 + (lb ^ ((row & 7) << 4));
                GLDS16(src, (char*)Qs + (w * 16 + i * 4) * 256);
            }
            asm volatile("s_waitcnt vmcnt(0)" ::: "memory");

            f32x4 po[8];
            #pragma unroll
            for (int i = 0; i < 8; ++i) { po[i][0]=0.f; po[i][1]=0.f; po[i][2]=0.f; po[i][3]=0.f; }

            #pragma unroll
            for (int kt = 0; kt < 4; ++kt) {
                const int kvb = kt * 64;
                f32x4 sA[4];
                #pragma unroll
                for (int i = 0; i < 4; ++i) { sA[i][0]=0.f; sA[i][1]=0.f; sA[i][2]=0.f; sA[i][3]=0.f; }
                #pragma unroll
                for (int ks = 0; ks < 4; ++ks) {
                    bf16x8 aa = *(const bf16x8*)((const char*)Qs + arow * 256 + ((ks * 64 + fg * 16) ^ aswz));
                    #pragma unroll
                    for (int fn = 0; fn < 4; ++fn) {
                        const int brow = kvb + fn * 16 + fr;
                        bf16x8 bb = *(const bf16x8*)(smem + brow * 256 + ((ks * 64 + fg * 16) ^ ((brow & 7) << 4)));
                        sA[fn] = __builtin_amdgcn_mfma_f32_16x16x32_bf16(aa, bb, sA[fn], 0, 0, 0);
                    }
                }
                #pragma unroll
                for (int fn = 0; fn < 4; ++fn)
                    #pragma unroll
                    for (int r = 0; r < 4; ++r)
                        Pw[(fg * 4 + r) * 68 + fn * 16 + fr] = f2b(gelu_fast(sA[fn][r]));
                asm volatile("s_waitcnt lgkmcnt(0)" ::: "memory");
                #pragma unroll
                for (int ks2 = 0; ks2 < 2; ++ks2) {
                    bf16x8 pa = *(const bf16x8*)((const char*)Pw + fr * 136 + ks2 * 64 + fg * 16);
                    #pragma unroll
                    for (int fn2 = 0; fn2 < 8; ++fn2) {
                        const int vrow = fn2 * 16 + fr;
                        bf16x8 bv = *(const bf16x8*)(smem + 65536 + vrow * 512 + kt * 128 + ((ks2 * 64 + fg * 16) ^ ((vrow & 7) << 4)));
                        po[fn2] = __builtin_amdgcn_mfma_f32_16x16x32_bf16(pa, bv, po[fn2], 0, 0, 0);
                    }
                }
            }
            const int rloc = w * 16 + fg * 4;
            #pragma unroll
            for (int r = 0; r < 4; ++r) {
                int gr = tb + rloc + r;
                if (gr < n_e) {
                    int p = plist[e * BT + gr];
                    float g = gv[p];
                    #pragma unroll
                    for (int fn2 = 0; fn2 < 8; ++fn2)
                        pairout[(size_t)p * 1024 + hd * DD + fn2 * 16 + fr] = f2b(g * po[fn2][r]);
                }
            }
        }
    }
}

// catb[:,1024:2048) = bf16(pairout[2m] + pairout[2m+1]), written pre-swizzled.
__global__ void combine_kernel(const ushort* __restrict__ po, ushort* __restrict__ catb)
{
    int i = blockIdx.x * blockDim.x + threadIdx.x;
    if (i >= BT * 128) return;
    int m = i >> 7, c = i & 127;
    const ushort* a = po + (size_t)(2 * m) * 1024 + c * 8;
    const ushort* b = po + (size_t)(2 * m + 1) * 1024 + c * 8;
    ushort4 a0 = *(const ushort4*)a, a1 = *(const ushort4*)(a + 4);
    ushort4 b0 = *(const ushort4*)b, b1 = *(const ushort4*)(b + 4);
    ushort4 o0, o1;
    o0.x = f2b(b2f(a0.x) + b2f(b0.x)); o0.y = f2b(b2f(a0.y) + b2f(b0.y));
    o0.z = f2b(b2f(a0.z) + b2f(b0.z)); o0.w = f2b(b2f(a0.w) + b2f(b0.w));
    o1.x = f2b(b2f(a1.x) + b2f(b1.x)); o1.y = f2b(b2f(a1.y) + b2f(b1.y));
    o1.z = f2b(b2f(a1.z) + b2f(b1.z)); o1.w = f2b(b2f(a1.w) + b2f(b1.w));
    char* dst = (char*)catb + (size_t)m * 4096 + 2048 + ((c * 16) ^ ((m & 7) << 4));
    *(ushort4*)dst = o0;
    *(ushort4*)(dst + 8) = o1;
}

// ---------------------------------------------------------------------------
extern "C" void kernel_launch(void* const* d_in, const int* in_sizes, int n_in,
                              void* d_out, int out_size, void* d_ws, size_t ws_size,
                              hipStream_t stream)
{
    const float* x     = (const float*)d_in[0];
    const float* w_in  = (const float*)d_in[1];
    const float* w_out = (const float*)d_in[2];
    const float* kf    = (const float*)d_in[3];
    const float* vf    = (const float*)d_in[4];
    float* out = (float*)d_out;

    // ---- workspace layout (bytes); total ~130.4 MB ----
    char* W = (char*)d_ws;
    ushort* hbq     = (ushort*)(W + 0);           // 4096x1024 bf16  8388608
    ushort* xb      = (ushort*)(W + 33554432);    // 4096x1024 bf16  8388608
    ushort* wib     = (ushort*)(W + 41943040);    // 4096x1024 bf16  8388608
    ushort* wob     = (ushort*)(W + 50331648);    // 1024x2048 bf16  4194304
    ushort* qb2     = (ushort*)(W + 54525952);    // 16x2048x128     8388608
    ushort* kb2     = (ushort*)(W + 62914560);    // 16x2048x128     8388608
    ushort* vtb     = (ushort*)(W + 71303168);    // 16x128x2048     8388608
    ushort* catb    = (ushort*)(W + 79691776);    // 4096x2048 bf16  16777216 (swizzled)
    ushort* pairout = (ushort*)(W + 96468992);    // 8192x1024 bf16  16777216
    float*  gv      = (float*)(W + 113246208);    // 8192 f32        32768
    int*    counts  = (int*)(W + 113278976);      // 16 (+pad)       64
    int*    plist   = (int*)(W + 113279040);      // 16x4096 int     262144
    int*    eidx    = (int*)(W + 113541184);      // 8192 int        32768
    ushort* kfb     = (ushort*)(W + 113573952);   // 16x8x256x128    8388608
    ushort* vtf     = (ushort*)(W + 121962560);   // 16x8x128x256    8388608

    // 1) PREP: wib/wob/kfb/vtf conversions + ROUTER (logits/gates/eidx/xb)
    prep<<<4608, 256, 0, stream>>>(w_in, w_out, kf, vf, x,
                                   wib, wob, kfb, vtf, gv, eidx, xb);

    // 2) gemm1 FUSED (+ cheap build_lists riders at END): hbq|qb|kb|vtb|plist
    gemm1_fused<<<1040, 256, 0, stream>>>(xb, wib, hbq, qb2, kb2, vtb,
                                          eidx, counts, plist);

    // 3) ATTN + FFN merged (independent jobs): catb[:,0:1024) | pairout
    attn_ffn<<<512, 512, 0, stream>>>(qb2, kb2, vtb, catb,
                                      hbq, gv, counts, plist, kfb, vtf, pairout);

    // 4) combine -> catb[:, 1024:2048)
    combine_kernel<<<2048, 256, 0, stream>>>(pairout, catb);

    // 5) out = cat @ w_out^T (catb swizzled A, wob swizzled B)
    gemm_bf16<0><<<dim3(8, 32), 256, 0, stream>>>(catb, 2048, wob, 2048, out, 1024, 2048);
}

// Round 32
// 209.618 us; speedup vs baseline: 1.0421x; 1.0421x over previous
//
#include <hip/hip_runtime.h>
#include <hip/hip_bf16.h>
#include <math.h>

#define E 1024
#define NEXP 16
#define HH 8
#define DD 128
#define SS 256
#define BB 2
#define TT 2048
#define BT 4096      // BB*TT

typedef __attribute__((ext_vector_type(8))) short bf16x8;
typedef __attribute__((ext_vector_type(4))) float f32x4;

#define GLDS16(g, s) __builtin_amdgcn_global_load_lds( \
    (const __attribute__((address_space(1))) void*)(g), \
    (__attribute__((address_space(3))) void*)(s), 16, 0, 0)

__device__ __forceinline__ ushort f2b(float f) {
    union { float f; unsigned u; } v; v.f = f;
    unsigned r = (v.u + 0x7FFFu + ((v.u >> 16) & 1u)) >> 16;
    return (ushort)r;
}
__device__ __forceinline__ float b2f(ushort u) {
    union { unsigned u; float f; } v; v.u = ((unsigned)u) << 16;
    return v.f;
}
// tanh-form gelu: x * sigmoid(2*0.79788456*(x + 0.044715 x^3)); err <1e-4 at |x|<1
__device__ __forceinline__ float gelu_fast(float x) {
    float u2 = x * x;
    float tu = x * (1.5957691216f + 0.0713548163f * u2);   // 2u
    float e = __expf(tu);
    float sig = 1.f - __builtin_amdgcn_rcpf(e + 1.f);      // e/(e+1)
    return x * sig;
}

// ---------------------------------------------------------------------------
// PREP (fused): blocks [0,2048) w_in->wib swz; [2048,3072) w_out->wob;
// [3072,3584) expert K/V -> kfb/vtf; [3584,4608) ROUTER (logits+top2+xb).
// ---------------------------------------------------------------------------
__global__ __launch_bounds__(256) void prep(
    const float* __restrict__ w_in, const float* __restrict__ w_out,
    const float* __restrict__ kf, const float* __restrict__ vf,
    const float* __restrict__ x,
    ushort* __restrict__ wib, ushort* __restrict__ wob,
    ushort* __restrict__ kfb, ushort* __restrict__ vtf,
    float* __restrict__ gval, int* __restrict__ eidx, ushort* __restrict__ xb)
{
    __shared__ float T[64][132];
    const int bx = blockIdx.x;
    const int t = threadIdx.x;

    if (bx >= 3584) {
        // ---- router part: 4 tokens per block, wave = one token ----
        const int m = (bx - 3584) * 4 + (t >> 6);
        const int lane = t & 63;

        const float* xp = x + (size_t)m * 1024 + lane * 4;
        float4 xv0 = *(const float4*)(xp);
        float4 xv1 = *(const float4*)(xp + 256);
        float4 xv2 = *(const float4*)(xp + 512);
        float4 xv3 = *(const float4*)(xp + 768);

        {
            const int swrow = (m & 7) << 4;
            char* xrow = (char*)xb + (size_t)m * 2048;
            ushort4 u;
            u.x = f2b(xv0.x); u.y = f2b(xv0.y); u.z = f2b(xv0.z); u.w = f2b(xv0.w);
            *(ushort4*)(xrow + ((lane * 8 + 0 * 512) ^ swrow)) = u;
            u.x = f2b(xv1.x); u.y = f2b(xv1.y); u.z = f2b(xv1.z); u.w = f2b(xv1.w);
            *(ushort4*)(xrow + ((lane * 8 + 1 * 512) ^ swrow)) = u;
            u.x = f2b(xv2.x); u.y = f2b(xv2.y); u.z = f2b(xv2.z); u.w = f2b(xv2.w);
            *(ushort4*)(xrow + ((lane * 8 + 2 * 512) ^ swrow)) = u;
            u.x = f2b(xv3.x); u.y = f2b(xv3.y); u.z = f2b(xv3.z); u.w = f2b(xv3.w);
            *(ushort4*)(xrow + ((lane * 8 + 3 * 512) ^ swrow)) = u;
        }

        float p[16];
        #pragma unroll
        for (int e = 0; e < 16; ++e) {
            const float* wp = w_in + (size_t)(4096 + e) * 1024 + lane * 4;
            float4 w0 = *(const float4*)(wp);
            float4 w1 = *(const float4*)(wp + 256);
            float4 w2 = *(const float4*)(wp + 512);
            float4 w3 = *(const float4*)(wp + 768);
            float s0 = xv0.x * w0.x + xv0.y * w0.y + xv0.z * w0.z + xv0.w * w0.w;
            float s1 = xv1.x * w1.x + xv1.y * w1.y + xv1.z * w1.z + xv1.w * w1.w;
            float s2 = xv2.x * w2.x + xv2.y * w2.y + xv2.z * w2.z + xv2.w * w2.w;
            float s3 = xv3.x * w3.x + xv3.y * w3.y + xv3.z * w3.z + xv3.w * w3.w;
            p[e] = (s0 + s1) + (s2 + s3);
        }
        #pragma unroll
        for (int d = 1; d < 64; d <<= 1) {
            #pragma unroll
            for (int e = 0; e < 16; ++e)
                p[e] += __shfl_xor(p[e], d);
        }
        float best = -1e30f; int bi = 0;
        #pragma unroll
        for (int e = 0; e < 16; ++e)
            if (p[e] > best) { best = p[e]; bi = e; }
        float best2 = -1e30f; int bi2 = 0;
        #pragma unroll
        for (int e = 0; e < 16; ++e)
            if (e != bi && p[e] > best2) { best2 = p[e]; bi2 = e; }

        if (lane == 0) {
            gval[m * 2 + 0] = 1.f / (1.f + __expf(-best));
            gval[m * 2 + 1] = 1.f / (1.f + __expf(-best2));
            eidx[m * 2 + 0] = bi;
            eidx[m * 2 + 1] = bi2;
        }
        return;
    }

    if (bx < 3072) {
        const float* in;
        ushort* outp;
        int kshift, i;
        if (bx < 2048) { in = w_in;  outp = wib; kshift = 10; i = (bx * 256 + t) * 8; }
        else           { in = w_out; outp = wob; kshift = 11; i = ((bx - 2048) * 256 + t) * 8; }
        int row = i >> kshift;
        int colb = (i - (row << kshift)) * 2;
        float4 f0 = *(const float4*)(in + i);
        float4 f1 = *(const float4*)(in + i + 4);
        ushort4 u0, u1;
        u0.x = f2b(f0.x); u0.y = f2b(f0.y); u0.z = f2b(f0.z); u0.w = f2b(f0.w);
        u1.x = f2b(f1.x); u1.y = f2b(f1.y); u1.z = f2b(f1.z); u1.w = f2b(f1.w);
        char* dst = (char*)outp + ((size_t)row << (kshift + 1)) + (colb ^ ((row & 7) << 4));
        *(ushort4*)dst = u0;
        *(ushort4*)(dst + 8) = u1;
        return;
    }

    // cvt_kv part
    const int idx = bx - 3072;
    const int st = idx & 3, eh = idx >> 2;
    const int s0 = st * 64;
    const float* kbp = kf + (size_t)eh * SS * DD + (size_t)s0 * DD;
    const float* vbp = vf + (size_t)eh * SS * DD + (size_t)s0 * DD;
    for (int i = t; i < 64 * 32; i += 256) {
        int r = i >> 5, c4 = i & 31;
        float4 f = *(const float4*)(kbp + (size_t)r * DD + c4 * 4);
        ushort4 u;
        u.x = f2b(f.x); u.y = f2b(f.y); u.z = f2b(f.z); u.w = f2b(f.w);
        *(ushort4*)((char*)kfb + ((size_t)eh * 256 + s0 + r) * 256 + ((c4 * 8) ^ ((r & 7) << 4))) = u;
    }
    for (int i = t; i < 64 * 32; i += 256) {
        int r = i >> 5, c4 = i & 31;
        float4 f = *(const float4*)(vbp + (size_t)r * DD + c4 * 4);
        T[r][c4 * 4 + 0] = f.x; T[r][c4 * 4 + 1] = f.y;
        T[r][c4 * 4 + 2] = f.z; T[r][c4 * 4 + 3] = f.w;
    }
    __syncthreads();
    int g = t >> 4, fr = t & 15;
    #pragma unroll
    for (int dd = 0; dd < 8; ++dd) {
        int d = g + dd * 16;
        ushort4 u;
        u.x = f2b(T[4 * fr + 0][d]); u.y = f2b(T[4 * fr + 1][d]);
        u.z = f2b(T[4 * fr + 2][d]); u.w = f2b(T[4 * fr + 3][d]);
        size_t ob = ((size_t)eh * 128 + d) * 512 + s0 * 2;
        *(ushort4*)((char*)vtf + ob + ((8 * fr) ^ ((d & 7) << 4))) = u;
    }
}

// ---------------------------------------------------------------------------
// bf16 MFMA GEMM (generic, used for gemm2): C = A*B^T, operands pre-swizzled.
// ---------------------------------------------------------------------------
template<int BF16OUT>
__global__ __launch_bounds__(256) void gemm_bf16(
    const ushort* __restrict__ A, int lda,
    const ushort* __restrict__ B, int ldb,
    void* __restrict__ Cv, int ldc, int K)
{
    __shared__ ushort As[128 * 64];
    __shared__ ushort Bs[128 * 64];
    const int t = threadIdx.x;
    const int l = t & 63, w = t >> 6;
    const int m0 = blockIdx.y * 128, n0 = blockIdx.x * 128;
    const int wr = w >> 1, wc = w & 1;
    const int fr = l & 15, fg = l >> 4;

    const int srow = w * 32 + (l >> 3);
    const int sboff = (l & 7) * 16;
    const char* Ag = (const char*)A + ((size_t)(m0 + srow) * lda) * 2 + sboff;
    const char* Bg = (const char*)B + ((size_t)(n0 + srow) * ldb) * 2 + sboff;
    const int aswz = (fr & 7) << 4;

    f32x4 acc[4][4];
    #pragma unroll
    for (int i = 0; i < 4; ++i)
        #pragma unroll
        for (int j = 0; j < 4; ++j) { acc[i][j][0]=0.f; acc[i][j][1]=0.f; acc[i][j][2]=0.f; acc[i][j][3]=0.f; }

    for (int k0b = 0; k0b < K * 2; k0b += 128) {
        #pragma unroll
        for (int i = 0; i < 4; ++i) {
            GLDS16(Ag + (size_t)(i * 8) * lda * 2 + k0b, (char*)As + (w * 32 + i * 8) * 128);
            GLDS16(Bg + (size_t)(i * 8) * ldb * 2 + k0b, (char*)Bs + (w * 32 + i * 8) * 128);
        }
        __syncthreads();
        #pragma unroll
        for (int ksub = 0; ksub < 2; ++ksub) {
            bf16x8 a[4], b[4];
            #pragma unroll
            for (int mi = 0; mi < 4; ++mi)
                a[mi] = *(const bf16x8*)((const char*)As + (wr * 64 + mi * 16 + fr) * 128 + ((ksub * 64 + fg * 16) ^ aswz));
            #pragma unroll
            for (int ni = 0; ni < 4; ++ni)
                b[ni] = *(const bf16x8*)((const char*)Bs + (wc * 64 + ni * 16 + fr) * 128 + ((ksub * 64 + fg * 16) ^ aswz));
            #pragma unroll
            for (int mi = 0; mi < 4; ++mi)
                #pragma unroll
                for (int ni = 0; ni < 4; ++ni)
                    acc[mi][ni] = __builtin_amdgcn_mfma_f32_16x16x32_bf16(a[mi], b[ni], acc[mi][ni], 0, 0, 0);
        }
        __syncthreads();
    }
    #pragma unroll
    for (int mi = 0; mi < 4; ++mi)
        #pragma unroll
        for (int ni = 0; ni < 4; ++ni) {
            const int row = m0 + wr * 64 + mi * 16 + fg * 4;
            const int col = n0 + wc * 64 + ni * 16 + fr;
            #pragma unroll
            for (int r = 0; r < 4; ++r) {
                if (BF16OUT)
                    ((ushort*)Cv)[(size_t)(row + r) * ldc + col] = f2b(acc[mi][ni][r]);
                else
                    ((float*)Cv)[(size_t)(row + r) * ldc + col] = acc[mi][ni][r];
            }
        }
}

// ---------------------------------------------------------------------------
// gemm1 FUSED + build_lists rider (riders at END; 2-phase wave-local scan).
//   lin < 1024:  gemm1 (bxn = lin&31, by = lin>>5), epilogue by region
//   lin >= 1024: build_lists for expert e = lin-1024
// Regions 0 & 3 stage through sh and write FULL 128-B lines per wave instr.
// ---------------------------------------------------------------------------
__global__ __launch_bounds__(256) void gemm1_fused(
    const ushort* __restrict__ A, const ushort* __restrict__ B,
    ushort* __restrict__ hbq,
    ushort* __restrict__ qb, ushort* __restrict__ kb,
    ushort* __restrict__ vtb,
    const int* __restrict__ eidx,
    int* __restrict__ counts, int* __restrict__ plist)
{
    __shared__ ushort sh[128 * 128];     // 32 KB: As|Bs during loop, Ts after
    const int lin = blockIdx.x;
    const int t = threadIdx.x;

    if (lin >= 1024) {
        // ---- build_lists (expert e): each wave owns tokens [w*2048,(w+1)*2048)
        int* ish = (int*)sh;             // ish[0..3] = per-wave counts
        const int e = lin - 1024;
        const int w = t >> 6, lane = t & 63;
        const int base = w * 2048;

        int cnt = 0;
        for (int c = 0; c < 2048; c += 64) {
            bool match = (eidx[base + c + lane] == e);
            unsigned long long mask = __ballot(match);
            cnt += __popcll(mask);
        }
        if (lane == 0) ish[w] = cnt;
        __syncthreads();
        int off = 0;
        #pragma unroll
        for (int i = 0; i < 4; ++i) if (i < w) off += ish[i];
        for (int c = 0; c < 2048; c += 64) {
            bool match = (eidx[base + c + lane] == e);
            unsigned long long mask = __ballot(match);
            int lpre = __popcll(mask & ((1ull << lane) - 1ull));
            if (match) plist[e * BT + off + lpre] = base + c + lane;
            off += __popcll(mask);
        }
        if (t == 0) counts[e] = ish[0] + ish[1] + ish[2] + ish[3];
        return;
    }

    ushort* As = sh;
    ushort* Bs = sh + 128 * 64;
    const int l = t & 63, w = t >> 6;
    const int bxn = lin & 31, by = lin >> 5;
    const int m0 = by * 128, n0 = bxn * 128;
    const int wr = w >> 1, wc = w & 1;
    const int fr = l & 15, fg = l >> 4;

    const int srow = w * 32 + (l >> 3);
    const int sboff = (l & 7) * 16;
    const char* Ag = (const char*)A + ((size_t)(m0 + srow) * 1024) * 2 + sboff;
    const char* Bg = (const char*)B + ((size_t)(n0 + srow) * 1024) * 2 + sboff;
    const int aswz = (fr & 7) << 4;

    f32x4 acc[4][4];
    #pragma unroll
    for (int i = 0; i < 4; ++i)
        #pragma unroll
        for (int j = 0; j < 4; ++j) { acc[i][j][0]=0.f; acc[i][j][1]=0.f; acc[i][j][2]=0.f; acc[i][j][3]=0.f; }

    for (int k0b = 0; k0b < 2048; k0b += 128) {
        #pragma unroll
        for (int i = 0; i < 4; ++i) {
            GLDS16(Ag + (size_t)(i * 8) * 2048 + k0b, (char*)As + (w * 32 + i * 8) * 128);
            GLDS16(Bg + (size_t)(i * 8) * 2048 + k0b, (char*)Bs + (w * 32 + i * 8) * 128);
        }
        __syncthreads();
        #pragma unroll
        for (int ksub = 0; ksub < 2; ++ksub) {
            bf16x8 a[4], b[4];
            #pragma unroll
            for (int mi = 0; mi < 4; ++mi)
                a[mi] = *(const bf16x8*)((const char*)As + (wr * 64 + mi * 16 + fr) * 128 + ((ksub * 64 + fg * 16) ^ aswz));
            #pragma unroll
            for (int ni = 0; ni < 4; ++ni)
                b[ni] = *(const bf16x8*)((const char*)Bs + (wc * 64 + ni * 16 + fr) * 128 + ((ksub * 64 + fg * 16) ^ aswz));
            #pragma unroll
            for (int mi = 0; mi < 4; ++mi)
                #pragma unroll
                for (int ni = 0; ni < 4; ++ni)
                    acc[mi][ni] = __builtin_amdgcn_mfma_f32_16x16x32_bf16(a[mi], b[ni], acc[mi][ni], 0, 0, 0);
        }
        __syncthreads();
    }

    const int region = bxn >> 3;   // 0=qf 1=q 2=k 3=v
    const int hd = bxn & 7;

    if (region == 0) {
        #pragma unroll
        for (int mi = 0; mi < 4; ++mi)
            #pragma unroll
            for (int ni = 0; ni < 4; ++ni) {
                const int cl = wc * 64 + ni * 16 + fr;
                #pragma unroll
                for (int r = 0; r < 4; ++r) {
                    const int rl = wr * 64 + mi * 16 + fg * 4 + r;
                    sh[rl * 128 + (cl ^ ((rl & 7) << 4))] = f2b(acc[mi][ni][r]);
                }
            }
        __syncthreads();
        const int r8 = l >> 3, u = l & 7;
        #pragma unroll
        for (int it = 0; it < 8; ++it) {
            const int slot = it * 4 + w;           // 0..31
            const int row = (slot & 15) * 8 + r8;  // 0..127
            const int c0 = (slot >> 4) * 64 + u * 8;
            bf16x8 v = *(const bf16x8*)&sh[row * 128 + (c0 ^ ((row & 7) << 4))];
            *(bf16x8*)&hbq[(size_t)(m0 + row) * 1024 + n0 + c0] = v;
        }
    } else if (region == 3) {
        const int bt = m0 >> 11;
        const int bh = bt * 8 + hd;
        const int tokbase = m0 & 2047;
        #pragma unroll
        for (int mi = 0; mi < 4; ++mi)
            #pragma unroll
            for (int ni = 0; ni < 4; ++ni) {
                const int cl = wc * 64 + ni * 16 + fr;    // d
                #pragma unroll
                for (int r = 0; r < 4; ++r) {
                    const int rl = wr * 64 + mi * 16 + fg * 4 + r;  // tok_local
                    sh[rl * 128 + ((cl + rl) & 127)] = f2b(acc[mi][ni][r]);
                }
            }
        __syncthreads();
        const int u = l & 7;          // memory unit (16 B) within 128-B segment
        #pragma unroll
        for (int it = 0; it < 8; ++it) {
            const int slot = it * 4 + w;            // 0..31
            const int dbase = (slot & 15) * 8;      // 0..120
            const int seg = slot >> 4;              // 0..1
            const int d = dbase + (l >> 3);
            const int tu = u ^ (d & 7);             // tok-unit feeding mem unit u
            bf16x8 v;
            #pragma unroll
            for (int j = 0; j < 8; ++j) {
                const int tl = seg * 64 + tu * 8 + j;
                v[j] = (short)sh[tl * 128 + ((d + tl) & 127)];
            }
            char* dst = (char*)vtb + (size_t)(bh * 128 + d) * 4096
                      + ((tokbase >> 6) + seg) * 128 + u * 16;
            *(bf16x8*)dst = v;
        }
    } else {
        #pragma unroll
        for (int mi = 0; mi < 4; ++mi)
            #pragma unroll
            for (int ni = 0; ni < 4; ++ni) {
                const int rl = wr * 64 + mi * 16 + fg * 4;
                const int cl = wc * 64 + ni * 16 + fr;
                #pragma unroll
                for (int r = 0; r < 4; ++r)
                    sh[(rl + r) * 128 + cl] = f2b(acc[mi][ni][r]);
            }
        __syncthreads();
        ushort* outb = (region == 1) ? qb : kb;
        #pragma unroll
        for (int it = 0; it < 4; ++it) {
            const int item = it * 256 + t;
            const int rloc = item >> 3, g = item & 7;
            const int rowg = m0 + rloc;
            const int tok = rowg & 2047, bt = rowg >> 11;
            const int sw = (tok & 7) << 4;
            char* rowbase = (char*)outb + ((size_t)((bt * 8 + hd) * 2048 + tok)) * 256;
            ushort lo[8], hi[8];
            #pragma unroll
            for (int jj = 0; jj < 8; ++jj) {
                const int j = g * 8 + jj;
                float t1 = b2f(sh[rloc * 128 + j]);
                float t2 = b2f(sh[rloc * 128 + 64 + j]);
                float invf = __expf(-(float)j * (9.210340371976184f / 64.f));
                float ang = (float)tok * invf;
                float s, c;
                sincosf(ang, &s, &c);
                lo[jj] = f2b(t1 * c - t2 * s);
                hi[jj] = f2b(t1 * s + t2 * c);
            }
            *(ushort4*)(rowbase + ((16 * g) ^ sw))        = *(ushort4*)&lo[0];
            *(ushort4*)(rowbase + (((16 * g) ^ sw) + 8))  = *(ushort4*)&lo[4];
            *(ushort4*)(rowbase + ((16 * g + 128) ^ sw))       = *(ushort4*)&hi[0];
            *(ushort4*)(rowbase + (((16 * g + 128) ^ sw) + 8)) = *(ushort4*)&hi[4];
        }
    }
}

// ---------------------------------------------------------------------------
// ATTN + FFN merged dispatch (independent jobs, disjoint block ranges).
//   lin < 256:   MFMA flash attention v5 (8 waves = 512 threads)
//   lin >= 256:  MoE FFN (waves 0-3 active; waves 4-7 exit after barrier)
// ---------------------------------------------------------------------------
__global__ __launch_bounds__(512, 1) void attn_ffn(
    const ushort* __restrict__ qb, const ushort* __restrict__ kb,
    const ushort* __restrict__ vtb, ushort* __restrict__ catb,
    const ushort* __restrict__ hbq,
    const float* __restrict__ gv,
    const int* __restrict__ counts,
    const int* __restrict__ plist,
    const ushort* __restrict__ kfb, const ushort* __restrict__ vtf,
    ushort* __restrict__ pairout)
{
    __shared__ __align__(16) char smem[156672];
    const int t = threadIdx.x, l = t & 63, w = t >> 6;
    const int fr = l & 15, fg = l >> 4;
    const int lin = blockIdx.x;

    if (lin < 256) {
        // =========================== attention ===========================
        ushort* Psb  = (ushort*)(smem + 131072);
        float*  LlSb = (float*)(smem + 149504);

        const int wl = w & 3, hh = w >> 2;
        const int bh = (lin & 7) * 2 + (lin >> 7);
        const int tpair = (lin >> 3) & 15;
        const int swz = (fr & 7) << 4;
        ushort* Pw = Psb + w * (16 * 72);

        #pragma unroll 1
        for (int pass = 0; pass < 2; ++pass) {
            const int qt = pass ? (31 - tpair) : tpair;
            const int qbase = qt * 64;
            const int nkt = (qt + 2) >> 1;          // 128-kv tiles
            const int qg = qbase + wl * 16 + fg * 4;

            bf16x8 qreg[4];
            {
                const char* qrow = (const char*)qb + ((size_t)(bh * 2048 + qbase + wl * 16 + fr)) * 256;
                #pragma unroll
                for (int ks = 0; ks < 4; ++ks)
                    qreg[ks] = *(const bf16x8*)(qrow + ((ks * 64 + fg * 16) ^ swz));
            }
            {
                const char* ksrc = (const char*)kb + ((size_t)(bh * 2048 + w * 16)) * 256;
                const char* vsrc = (const char*)vtb + ((size_t)(bh * 128 + w * 16)) * 4096;
                #pragma unroll
                for (int i = 0; i < 4; ++i) {
                    GLDS16(ksrc + (size_t)(i * 4 + (l >> 4)) * 256 + (l & 15) * 16,
                           smem + (w * 16 + i * 4) * 256);
                    GLDS16(vsrc + (size_t)(i * 4 + (l >> 4)) * 4096 + (l & 15) * 16,
                           smem + 65536 + (w * 16 + i * 4) * 256);
                }
            }

            f32x4 po[8];
            #pragma unroll
            for (int i = 0; i < 8; ++i) { po[i][0]=0.f; po[i][1]=0.f; po[i][2]=0.f; po[i][3]=0.f; }
            float lrow[4] = {0.f, 0.f, 0.f, 0.f};

            asm volatile("s_waitcnt vmcnt(0)" ::: "memory");
            __syncthreads();

            for (int kt = 0; kt < nkt; ++kt) {
                const int cur = kt & 1;
                if (kt + 1 < nkt) {
                    const int kvn = (kt + 1) * 128;
                    const char* ksrc = (const char*)kb + ((size_t)(bh * 2048 + kvn + w * 16)) * 256;
                    const char* vsrc = (const char*)vtb + ((size_t)(bh * 128 + w * 16)) * 4096 + kvn * 2;
                    #pragma unroll
                    for (int i = 0; i < 4; ++i) {
                        GLDS16(ksrc + (size_t)(i * 4 + (l >> 4)) * 256 + (l & 15) * 16,
                               smem + (cur ^ 1) * 32768 + (w * 16 + i * 4) * 256);
                        GLDS16(vsrc + (size_t)(i * 4 + (l >> 4)) * 4096 + (l & 15) * 16,
                               smem + 65536 + (cur ^ 1) * 32768 + (w * 16 + i * 4) * 256);
                    }
                }
                const int kvb = kt * 128;

                f32x4 s[4];
                #pragma unroll
                for (int i = 0; i < 4; ++i) { s[i][0]=0.f; s[i][1]=0.f; s[i][2]=0.f; s[i][3]=0.f; }
                __builtin_amdgcn_s_setprio(1);
                #pragma unroll
                for (int ks = 0; ks < 4; ++ks) {
                    #pragma unroll
                    for (int fn = 0; fn < 4; ++fn) {
                        const int brow = hh * 64 + fn * 16 + fr;
                        bf16x8 bb = *(const bf16x8*)(smem + cur * 32768 + brow * 256 + ((ks * 64 + fg * 16) ^ swz));
                        s[fn] = __builtin_amdgcn_mfma_f32_16x16x32_bf16(qreg[ks], bb, s[fn], 0, 0, 0);
                    }
                }
                __builtin_amdgcn_s_setprio(0);

                const int colbase = kvb + hh * 64;
                const bool needmask = (colbase + 64 > qbase + wl * 16);
                float ps[4] = {0.f, 0.f, 0.f, 0.f};
                #pragma unroll
                for (int fn = 0; fn < 4; ++fn)
                    #pragma unroll
                    for (int r = 0; r < 4; ++r) {
                        float v = s[fn][r] * 0.08838834764831845f;
                        bool masked = needmask && (colbase + fn * 16 + fr > qg + r);
                        float p = masked ? 0.f : __expf(v);
                        ps[r] += p;
                        Pw[(fg * 4 + r) * 72 + fn * 16 + fr] = f2b(p);
                    }
                #pragma unroll
                for (int r = 0; r < 4; ++r) {
                    float s2 = ps[r];
                    s2 += __shfl_xor(s2, 1);
                    s2 += __shfl_xor(s2, 2);
                    s2 += __shfl_xor(s2, 4);
                    s2 += __shfl_xor(s2, 8);
                    lrow[r] += s2;
                }

                asm volatile("s_waitcnt lgkmcnt(0)" ::: "memory");
                __builtin_amdgcn_sched_barrier(0);

                __builtin_amdgcn_s_setprio(1);
                #pragma unroll
                for (int ks2 = 0; ks2 < 2; ++ks2) {
                    bf16x8 pa = *(const bf16x8*)((const char*)Pw + fr * 144 + ks2 * 64 + fg * 16);
                    #pragma unroll
                    for (int fn2 = 0; fn2 < 8; ++fn2) {
                        const int vrow = fn2 * 16 + fr;
                        bf16x8 bv = *(const bf16x8*)(smem + 65536 + cur * 32768 + vrow * 256 + ((hh * 128 + ks2 * 64 + fg * 16) ^ swz));
                        po[fn2] = __builtin_amdgcn_mfma_f32_16x16x32_bf16(pa, bv, po[fn2], 0, 0, 0);
                    }
                }
                __builtin_amdgcn_s_setprio(0);

                asm volatile("s_waitcnt vmcnt(0)" ::: "memory");
                __syncthreads();
            }

            // ---- epilogue: plain two-way sum merge (no max tracking) ----
            if (fr == 0) {
                #pragma unroll
                for (int r = 0; r < 4; ++r)
                    LlSb[w * 16 + fg * 4 + r] = lrow[r];
            }
            __syncthreads();
            float linv[4];
            #pragma unroll
            for (int r = 0; r < 4; ++r)
                linv[r] = 1.f / (lrow[r] + LlSb[(w ^ 4) * 16 + fg * 4 + r]);
            float* PO = (float*)smem;   // 32 KB scratch (K buffers dead here)
            if (hh == 1) {
                #pragma unroll
                for (int fn2 = 0; fn2 < 8; ++fn2)
                    #pragma unroll
                    for (int r = 0; r < 4; ++r)
                        PO[(wl * 16 + fg * 4 + r) * 128 + fn2 * 16 + fr] = po[fn2][r];
            }
            __syncthreads();
            if (hh == 0) {
                const int mg = (bh >> 3) * 2048 + qbase + wl * 16 + fg * 4;
                #pragma unroll
                for (int r = 0; r < 4; ++r) {
                    const int rswz = ((mg + r) & 7) << 4;
                    #pragma unroll
                    for (int fn2 = 0; fn2 < 8; ++fn2) {
                        float v = po[fn2][r] + PO[(wl * 16 + fg * 4 + r) * 128 + fn2 * 16 + fr];
                        int colb = ((bh & 7) * 128 + fn2 * 16 + fr) * 2;
                        *(ushort*)((char*)catb + (size_t)(mg + r) * 4096 + (colb ^ rswz)) = f2b(v * linv[r]);
                    }
                }
            }
            __syncthreads();   // protect Ks reuse before next pass's staging
        }
        return;
    }

    // ============================== ffn ==============================
    {
        ushort* Qs  = (ushort*)(smem + 131072);
        ushort* Psb = (ushort*)(smem + 147456);

        const int idx = lin - 256;
        const int half = idx & 1, hd = (idx >> 1) & 7, e = idx >> 4;
        const int eh = e * HH + hd;
        const int n_e = counts[e];

        if (w < 4) {
            const char* kbase = (const char*)kfb + (size_t)eh * 65536;
            const char* vbase = (const char*)vtf + (size_t)eh * 65536;
            #pragma unroll
            for (int i = 0; i < 16; ++i) {
                GLDS16(kbase + (w * 64 + i * 4) * 256 + l * 16, smem + (w * 64 + i * 4) * 256);
                GLDS16(vbase + w * 16384 + i * 1024 + l * 16, smem + 65536 + w * 16384 + i * 1024);
            }
        }
        __syncthreads();
        if (w >= 4) return;

        const int arow = w * 16 + fr;
        const int aswz = (arow & 7) << 4;
        ushort* Pw = Psb + w * (16 * 72);
        const int rl4 = l >> 4;
        const int lb = (l & 15) * 16;

        for (int tb = half * 64; tb < n_e; tb += 128) {
            #pragma unroll
            for (int i = 0; i < 4; ++i) {
                int row = w * 16 + i * 4 + rl4;
                int gr = tb + row;
                int p = plist[e * BT + min(gr, n_e - 1)];
                int m = p >> 1;
                const char* src = (const char*)hbq + (size_t)m * 2048 + hd * 256 + (lb ^ ((row & 7) << 4));
                GLDS16(src, (char*)Qs + (w * 16 + i * 4) * 256);
            }
            asm volatile("s_waitcnt vmcnt(0)" ::: "memory");

            f32x4 po[8];
            #pragma unroll
            for (int i = 0; i < 8; ++i) { po[i][0]=0.f; po[i][1]=0.f; po[i][2]=0.f; po[i][3]=0.f; }

            #pragma unroll
            for (int kt = 0; kt < 4; ++kt) {
                const int kvb = kt * 64;
                f32x4 sA[4];
                #pragma unroll
                for (int i = 0; i < 4; ++i) { sA[i][0]=0.f; sA[i][1]=0.f; sA[i][2]=0.f; sA[i][3]=0.f; }
                #pragma unroll
                for (int ks = 0; ks < 4; ++ks) {
                    bf16x8 aa = *(const bf16x8*)((const char*)Qs + arow * 256 + ((ks * 64 + fg * 16) ^ aswz));
                    #pragma unroll
                    for (int fn = 0; fn < 4; ++fn) {
                        const int brow = kvb + fn * 16 + fr;
                        bf16x8 bb = *(const bf16x8*)(smem + brow * 256 + ((ks * 64 + fg * 16) ^ ((brow & 7) << 4)));
                        sA[fn] = __builtin_amdgcn_mfma_f32_16x16x32_bf16(aa, bb, sA[fn], 0, 0, 0);
                    }
                }
                #pragma unroll
                for (int fn = 0; fn < 4; ++fn)
                    #pragma unroll
                    for (int r = 0; r < 4; ++r)
                        Pw[(fg * 4 + r) * 72 + fn * 16 + fr] = f2b(gelu_fast(sA[fn][r]));
                asm volatile("s_waitcnt lgkmcnt(0)" ::: "memory");
                #pragma unroll
                for (int ks2 = 0; ks2 < 2; ++ks2) {
                    bf16x8 pa = *(const bf16x8*)((const char*)Pw + fr * 144 + ks2 * 64 + fg * 16);
                    #pragma unroll
                    for (int fn2 = 0; fn2 < 8; ++fn2) {
                        const int vrow = fn2 * 16 + fr;
                        bf16x8 bv = *(const bf16x8*)(smem + 65536 + vrow * 512 + kt * 128 + ((ks2 * 64 + fg * 16) ^ ((vrow & 7) << 4)));
                        po[fn2] = __builtin_amdgcn_mfma_f32_16x16x32_bf16(pa, bv, po[fn2], 0, 0, 0);
                    }
                }
            }
            const int rloc = w * 16 + fg * 4;
            #pragma unroll
            for (int r = 0; r < 4; ++r) {
                int gr = tb + rloc + r;
                if (gr < n_e) {
                    int p = plist[e * BT + gr];
                    float g = gv[p];
                    #pragma unroll
                    for (int fn2 = 0; fn2 < 8; ++fn2)
                        pairout[(size_t)p * 1024 + hd * DD + fn2 * 16 + fr] = f2b(g * po[fn2][r]);
                }
            }
        }
    }
}

// catb[:,1024:2048) = bf16(pairout[2m] + pairout[2m+1]), written pre-swizzled.
__global__ void combine_kernel(const ushort* __restrict__ po, ushort* __restrict__ catb)
{
    int i = blockIdx.x * blockDim.x + threadIdx.x;
    if (i >= BT * 128) return;
    int m = i >> 7, c = i & 127;
    const ushort* a = po + (size_t)(2 * m) * 1024 + c * 8;
    const ushort* b = po + (size_t)(2 * m + 1) * 1024 + c * 8;
    ushort4 a0 = *(const ushort4*)a, a1 = *(const ushort4*)(a + 4);
    ushort4 b0 = *(const ushort4*)b, b1 = *(const ushort4*)(b + 4);
    ushort4 o0, o1;
    o0.x = f2b(b2f(a0.x) + b2f(b0.x)); o0.y = f2b(b2f(a0.y) + b2f(b0.y));
    o0.z = f2b(b2f(a0.z) + b2f(b0.z)); o0.w = f2b(b2f(a0.w) + b2f(b0.w));
    o1.x = f2b(b2f(a1.x) + b2f(b1.x)); o1.y = f2b(b2f(a1.y) + b2f(b1.y));
    o1.z = f2b(b2f(a1.z) + b2f(b1.z)); o1.w = f2b(b2f(a1.w) + b2f(b1.w));
    char* dst = (char*)catb + (size_t)m * 4096 + 2048 + ((c * 16) ^ ((m & 7) << 4));
    *(ushort4*)dst = o0;
    *(ushort4*)(dst + 8) = o1;
}

// ---------------------------------------------------------------------------
extern "C" void kernel_launch(void* const* d_in, const int* in_sizes, int n_in,
                              void* d_out, int out_size, void* d_ws, size_t ws_size,
                              hipStream_t stream)
{
    const float* x     = (const float*)d_in[0];
    const float* w_in  = (const float*)d_in[1];
    const float* w_out = (const float*)d_in[2];
    const float* kf    = (const float*)d_in[3];
    const float* vf    = (const float*)d_in[4];
    float* out = (float*)d_out;

    // ---- workspace layout (bytes); total ~130.4 MB ----
    char* W = (char*)d_ws;
    ushort* hbq     = (ushort*)(W + 0);           // 4096x1024 bf16  8388608
    ushort* xb      = (ushort*)(W + 33554432);    // 4096x1024 bf16  8388608
    ushort* wib     = (ushort*)(W + 41943040);    // 4096x1024 bf16  8388608
    ushort* wob     = (ushort*)(W + 50331648);    // 1024x2048 bf16  4194304
    ushort* qb2     = (ushort*)(W + 54525952);    // 16x2048x128     8388608
    ushort* kb2     = (ushort*)(W + 62914560);    // 16x2048x128     8388608
    ushort* vtb     = (ushort*)(W + 71303168);    // 16x128x2048     8388608
    ushort* catb    = (ushort*)(W + 79691776);    // 4096x2048 bf16  16777216 (swizzled)
    ushort* pairout = (ushort*)(W + 96468992);    // 8192x1024 bf16  16777216
    float*  gv      = (float*)(W + 113246208);    // 8192 f32        32768
    int*    counts  = (int*)(W + 113278976);      // 16 (+pad)       64
    int*    plist   = (int*)(W + 113279040);      // 16x4096 int     262144
    int*    eidx    = (int*)(W + 113541184);      // 8192 int        32768
    ushort* kfb     = (ushort*)(W + 113573952);   // 16x8x256x128    8388608
    ushort* vtf     = (ushort*)(W + 121962560);   // 16x8x128x256    8388608

    // 1) PREP: wib/wob/kfb/vtf conversions + ROUTER (logits/gates/eidx/xb)
    prep<<<4608, 256, 0, stream>>>(w_in, w_out, kf, vf, x,
                                   wib, wob, kfb, vtf, gv, eidx, xb);

    // 2) gemm1 FUSED (+ cheap build_lists riders at END): hbq|qb|kb|vtb|plist
    gemm1_fused<<<1040, 256, 0, stream>>>(xb, wib, hbq, qb2, kb2, vtb,
                                          eidx, counts, plist);

    // 3) ATTN + FFN merged (independent jobs): catb[:,0:1024) | pairout
    attn_ffn<<<512, 512, 0, stream>>>(qb2, kb2, vtb, catb,
                                      hbq, gv, counts, plist, kfb, vtf, pairout);

    // 4) combine -> catb[:, 1024:2048)
    combine_kernel<<<2048, 256, 0, stream>>>(pairout, catb);

    // 5) out = cat @ w_out^T (catb swizzled A, wob swizzled B)
    gemm_bf16<0><<<dim3(8, 32), 256, 0, stream>>>(catb, 2048, wob, 2048, out, 1024, 2048);
}